// Round 6
// baseline (457.736 us; speedup 1.0000x reference)
//
#include <hip/hip_runtime.h>

// Link_Embedding: out[e] = concat(X[src[e]], X[dst[e]])
// X: 100000 x 128 fp32 (51.2 MB), idx: 320000 x 2 int32, out: 320000 x 256 fp32 (327.7 MB).
//
// R9 = R8 with ONE change: emit-path stores are NONTEMPORAL (was normal).
// A/B to discriminate two theories for R8's regression (454us vs R5 385us;
// kernel-land 248 vs 180 -- the ~206us poison memset sits inside the timed
// region, and no dispatch of ours ever exceeds the ~203us top-5 cutoff):
//   (1) POLLUTION: R8's normal emit stores write-allocate 109MB into L2/L3,
//       evicting X and degrading BOTH paths. nt stores bypass -> expect
//       dur ~360-390 (kernel-land ~155-185).
//   (2) SHARED WALL: random 512B accesses (either direction) drain through a
//       shared per-access-limited resource (~3.6G acc/s). nt flip changes
//       nothing -> expect dur ~450. Then hybrids are dead; pure gather (R5)
//       is within ~2x of a structural floor and becomes the keeper.
// Everything else identical to R8: f=0.34 split (S_EDGES=108800 via binned
// emit, rest via R5 gather), emit blocks first, prelude on 217.6K endpoints.

typedef float f4 __attribute__((ext_vector_type(4)));

#define N_EDGES   320000
#define N_NODES   100000
#define BSHIFT    6
#define NB        1563            // ceil(100000 / 64) buckets
#define S_EDGES   108800          // edges routed through scatter/emit path
#define G_EDGES   (N_EDGES - S_EDGES)   // 211200 via gather
#define NENT      (2 * S_EDGES)   // 217600 binned endpoints

// Gather-path geometry
#define BLOCK 256
#define UNROLL 8
#define EDGES_PER_BLOCK 32
#define GATHER_BLOCKS (G_EDGES / EDGES_PER_BLOCK)   // 6600 exact
#define FUSED_BLOCKS (NB + GATHER_BLOCKS)

// Workspace layout (bytes)
#define OFF_OFF   0               // int[NB+1]
#define CUR_OFF   8192            // int[NB]
#define ENT_OFF   16384           // int2[NENT]
#define WS_NEED   (ENT_OFF + (size_t)NENT * 8)

// ---------------- prelude ----------------

__global__ void k0_zero(int* __restrict__ off) {
    const int i = blockIdx.x * 256 + threadIdx.x;
    if (i <= NB) off[i] = 0;
}

__global__ void k1_hist(const int2* __restrict__ idx, int* __restrict__ off) {
    const int e = blockIdx.x * 256 + threadIdx.x;   // grid covers S_EDGES exactly
    const int2 p = idx[e];
    atomicAdd(&off[p.x >> BSHIFT], 1);
    atomicAdd(&off[p.y >> BSHIFT], 1);
}

__global__ void k2_scan(int* __restrict__ off, int* __restrict__ cur) {
    __shared__ int c[NB];
    for (int i = threadIdx.x; i < NB; i += 256) c[i] = off[i];
    __syncthreads();
    if (threadIdx.x < 64) {
        const int lane = threadIdx.x;
        const int lo = lane * 25;
        const int hi = (lo + 25 < NB) ? lo + 25 : NB;  // ceil(1563/64)=25
        int run = 0;
        for (int j = lo; j < hi; ++j) { const int t = c[j]; c[j] = run; run += t; }
        int inc = run;
        #pragma unroll
        for (int d = 1; d < 64; d <<= 1) {
            const int o = __shfl_up(inc, d, 64);
            if (lane >= d) inc += o;
        }
        const int exc = inc - run;
        for (int j = lo; j < hi; ++j) c[j] += exc;
        if (lane == 63) off[NB] = inc;  // = NENT
    }
    __syncthreads();
    for (int i = threadIdx.x; i < NB; i += 256) { off[i] = c[i]; cur[i] = c[i]; }
}

__global__ void k3_scatter(const int2* __restrict__ idx, int* __restrict__ cur,
                           int2* __restrict__ ent) {
    const int e = blockIdx.x * 256 + threadIdx.x;   // grid covers S_EDGES exactly
    const int2 p = idx[e];
    const int a = atomicAdd(&cur[p.x >> BSHIFT], 1);
    ent[a] = make_int2(p.x, 2 * e);
    const int b = atomicAdd(&cur[p.y >> BSHIFT], 1);
    ent[b] = make_int2(p.y, 2 * e + 1);
}

// ---------------- fused: emit blocks [0,NB) + gather blocks [NB,...) --------

__global__ __launch_bounds__(BLOCK) void k4_fused(
    const f4* __restrict__ X, const int* __restrict__ off,
    const int2* __restrict__ ent, const int* __restrict__ idx,
    f4* __restrict__ out)
{
    if (blockIdx.x < NB) {
        // ---- emit path: one block per 64-node bucket (32KB L1-hot slice) ----
        const int b    = blockIdx.x;
        const int lane = threadIdx.x & 63;
        const int wave = threadIdx.x >> 6;
        const int half = lane >> 5;
        const int col  = lane & 31;
        const int start = off[b];
        const int end   = off[b + 1];
        for (int i = start + wave * 2 + half; i < end; i += 8) {
            const int2 en = ent[i];             // (node, 2*e+side)
            const f4 v = X[(en.x << 5) + col];
            // NT store: bypass L2/L3 -> no write-allocate pollution of X.
            __builtin_nontemporal_store(
                v, &out[(long long)(en.y >> 1) * 64 + ((en.y & 1) << 5) + col]);
        }
    } else {
        // ---- gather path: edges [S_EDGES, N_EDGES), R5 structure ----
        const int gb   = blockIdx.x - NB;
        const int lane = threadIdx.x & 63;
        const int wave = __builtin_amdgcn_readfirstlane((int)(threadIdx.x >> 6));
        const int ebase = S_EDGES + gb * EDGES_PER_BLOCK + wave * UNROLL;

        int2 p[UNROLL];
        const int2* __restrict__ ip = (const int2*)idx + ebase;
        #pragma unroll
        for (int k = 0; k < UNROLL; ++k) p[k] = ip[k];

        const int which = lane >> 5;
        const int col   = lane & 31;

        f4 v[UNROLL];
        #pragma unroll
        for (int k = 0; k < UNROLL; ++k) {
            const int row = which ? p[k].y : p[k].x;
            v[k] = X[(long long)row * 32 + col];
        }

        f4* __restrict__ ob = out + (long long)ebase * 64 + lane;
        #pragma unroll
        for (int k = 0; k < UNROLL; ++k)
            __builtin_nontemporal_store(v[k], ob + (long long)k * 64);
    }
}

// ---------------- fallback: pure gather over all edges ----------------

__global__ __launch_bounds__(BLOCK) void link_embed_gather(
    const f4* __restrict__ X, const int* __restrict__ idx, f4* __restrict__ out)
{
    const int lane = threadIdx.x & 63;
    const int wave = __builtin_amdgcn_readfirstlane((int)(threadIdx.x >> 6));
    const int ebase = blockIdx.x * EDGES_PER_BLOCK + wave * UNROLL;

    int2 p[UNROLL];
    const int2* __restrict__ ip = (const int2*)idx + ebase;
    #pragma unroll
    for (int k = 0; k < UNROLL; ++k) p[k] = ip[k];

    const int which = lane >> 5;
    const int col   = lane & 31;

    f4 v[UNROLL];
    #pragma unroll
    for (int k = 0; k < UNROLL; ++k) {
        const int row = which ? p[k].y : p[k].x;
        v[k] = X[(long long)row * 32 + col];
    }

    f4* __restrict__ ob = out + (long long)ebase * 64 + lane;
    #pragma unroll
    for (int k = 0; k < UNROLL; ++k)
        __builtin_nontemporal_store(v[k], ob + (long long)k * 64);
}

// ---------------- host ----------------

extern "C" void kernel_launch(void* const* d_in, const int* in_sizes, int n_in,
                              void* d_out, int out_size, void* d_ws, size_t ws_size,
                              hipStream_t stream) {
    const f4*   X    = (const f4*)d_in[0];
    const int*  idx  = (const int*)d_in[1];
    const int2* idx2 = (const int2*)d_in[1];
    f4*         out  = (f4*)d_out;

    if (d_ws == nullptr || ws_size < WS_NEED) {
        link_embed_gather<<<N_EDGES / EDGES_PER_BLOCK, BLOCK, 0, stream>>>(X, idx, out);
        return;
    }

    int*  off = (int*)((char*)d_ws + OFF_OFF);
    int*  cur = (int*)((char*)d_ws + CUR_OFF);
    int2* ent = (int2*)((char*)d_ws + ENT_OFF);

    k0_zero   <<<(NB + 256) / 256, 256, 0, stream>>>(off);
    k1_hist   <<<S_EDGES / 256, 256, 0, stream>>>(idx2, off);
    k2_scan   <<<1, 256, 0, stream>>>(off, cur);
    k3_scatter<<<S_EDGES / 256, 256, 0, stream>>>(idx2, cur, ent);
    k4_fused  <<<FUSED_BLOCKS, BLOCK, 0, stream>>>(X, off, ent, idx, out);
}